// Round 1
// 492.729 us; speedup vs baseline: 1.1165x; 1.1165x over previous
//
#include <hip/hip_runtime.h>
#include <hip/hip_bf16.h>
#include <stdint.h>

#define B_DIM 256
#define I_DIM 128
#define C_DIM 1024
#define N_DIM 512            // U*S
#define KC    (C_DIM * I_DIM)
#define WC    (N_DIM * I_DIM)

typedef __bf16 bf16;
typedef __attribute__((ext_vector_type(4))) __bf16 bf16x4;
typedef __attribute__((ext_vector_type(8))) __bf16 bf16x8;
typedef __attribute__((ext_vector_type(4))) float f32x4;

__device__ __forceinline__ void async_copy16(const void* g, void* l) {
  __builtin_amdgcn_global_load_lds(
      (const __attribute__((address_space(1))) uint32_t*)g,
      (__attribute__((address_space(3))) uint32_t*)l, 16, 0, 0);
}

// ---------------------------------------------------------------------------
// Kernel 1: xT[b][c][i] = (bf16) x[b][i][c].  64x64 tiles.
// Load: float4 over c (16 B/lane).  Store: bf16x8 over i (16 B/lane).
// LDS stride 65: both phases 2-way bank-aliased (free).
// ---------------------------------------------------------------------------
__global__ void __launch_bounds__(256)
transpose_cast(const float* __restrict__ x, bf16* __restrict__ xT) {
  __shared__ float tile[64][65];
  const int c0 = blockIdx.x * 64;
  const int i0 = blockIdx.y * 64;
  const int b  = blockIdx.z;
  const int t  = threadIdx.x;
  const int sub = t >> 4;               // 0..15
  const int cg  = t & 15;               // 0..15
  const float* xb = x + (size_t)b * (I_DIM * C_DIM);
#pragma unroll
  for (int r = 0; r < 4; ++r) {
    const int i = r * 16 + sub;
    const float4 v = *(const float4*)&xb[(size_t)(i0 + i) * C_DIM + c0 + cg * 4];
    tile[i][cg * 4 + 0] = v.x; tile[i][cg * 4 + 1] = v.y;
    tile[i][cg * 4 + 2] = v.z; tile[i][cg * 4 + 3] = v.w;
  }
  __syncthreads();
  bf16* xTb = xT + (size_t)b * KC;
#pragma unroll
  for (int r = 0; r < 2; ++r) {
    const int c  = r * 32 + (t >> 3);   // 0..63
    const int ic = (t & 7) * 8;         // i-chunk of 8
    bf16x8 o;
#pragma unroll
    for (int k = 0; k < 8; ++k) o[k] = (bf16)tile[ic + k][c];
    *(bf16x8*)&xTb[(size_t)(c0 + c) * I_DIM + i0 + ic] = o;
  }
}

// ---------------------------------------------------------------------------
// Kernel 2: streaming split-K GEMM.
//   sj[b][n] += sum_{c in chunk} sum_i xT[b][c][i] * W[c][n][i]
// Grid 256 blocks (1/CU): 8 n-blocks (N-tile 64) x 32 c-chunks (32 c each),
// XCD-grouped so the 8 n-blocks sharing a c-chunk share one XCD L2.
// Per step (half-c = 64 i): stage A-slice 32 KB (bf16) + W-slice 16 KB (f32)
// via global_load_lds into a ring of 3 LDS buffers (144 KB total, 8 waves).
// Counted vmcnt(12) keeps 2 steps (96 KB/CU) in flight across raw barriers:
// HBM pipe never drains.  16B-chunk XOR swizzle (slot ^= row&7) on the
// global source AND the ds_read -> 2-way bank aliasing (free).
// ---------------------------------------------------------------------------
__device__ __forceinline__ void stage_step(
    const bf16* __restrict__ xT, const float* __restrict__ W,
    short* Asl, float* Wsl, int tid, int c, int h, int n0) {
  // A: 256 m x 64 i bf16 = 2048 x 16 B chunks, 4 per thread.
  const int ch = tid & 7;
  const size_t abase = (size_t)c * I_DIM + h * 64;
#pragma unroll
  for (int p = 0; p < 4; ++p) {
    const int m   = p * 64 + (tid >> 3);
    const int csw = ch ^ (m & 7);                       // inverse-swz source
    async_copy16(xT + (size_t)m * KC + abase + csw * 8,
                 &Asl[(p * 512 + tid) * 8]);            // linear LDS dest
  }
  // W: 64 n x 64 i f32 = 1024 x 16 B chunks, 2 per thread.
  const int s = tid & 15;
  const size_t wbase = (size_t)c * WC + h * 64;
#pragma unroll
  for (int p = 0; p < 2; ++p) {
    const int n   = p * 32 + (tid >> 4);
    const int ssw = s ^ (n & 7);
    async_copy16(W + wbase + (size_t)(n0 + n) * I_DIM + ssw * 4,
                 &Wsl[(p * 512 + tid) * 4]);
  }
}

__device__ __forceinline__ void compute_step(
    const short* Asl, const float* Wsl,
    int wm, int wn, int l15, int lq, f32x4 (&acc)[4][2]) {
#pragma unroll
  for (int ks = 0; ks < 2; ++ks) {                      // two 32-i MFMA slices
    bf16x8 a[4];
#pragma unroll
    for (int mt = 0; mt < 4; ++mt) {
      const int m  = wm * 64 + mt * 16 + l15;
      const int ch = (ks * 4 + lq) ^ (l15 & 7);         // read-side swizzle
      a[mt] = *(const bf16x8*)&Asl[m * 64 + ch * 8];
    }
    bf16x8 b[2];
#pragma unroll
    for (int nt = 0; nt < 2; ++nt) {
      const int n  = wn * 32 + nt * 16 + l15;
      const int s0 = (ks * 8 + lq * 2)     ^ (l15 & 7);
      const int s1 = (ks * 8 + lq * 2 + 1) ^ (l15 & 7);
      const f32x4 lo = *(const f32x4*)&Wsl[n * 64 + s0 * 4];
      const f32x4 hi = *(const f32x4*)&Wsl[n * 64 + s1 * 4];
      bf16x8 bb;
      bb[0] = (bf16)lo[0]; bb[1] = (bf16)lo[1];
      bb[2] = (bf16)lo[2]; bb[3] = (bf16)lo[3];
      bb[4] = (bf16)hi[0]; bb[5] = (bf16)hi[1];
      bb[6] = (bf16)hi[2]; bb[7] = (bf16)hi[3];
      b[nt] = bb;
    }
#pragma unroll
    for (int mt = 0; mt < 4; ++mt)
#pragma unroll
      for (int nt = 0; nt < 2; ++nt)
        acc[mt][nt] = __builtin_amdgcn_mfma_f32_16x16x32_bf16(
            a[mt], b[nt], acc[mt][nt], 0, 0, 0);
  }
}

__global__ void __launch_bounds__(512, 2)
gemm_kernel(const bf16* __restrict__ xT, const float* __restrict__ W,
            float* __restrict__ sj) {
  __shared__ short As[3][B_DIM * 64];   // 3 x 32 KB
  __shared__ float Ws[3][64 * 64];      // 3 x 16 KB -> 144 KB total
  const int tid  = threadIdx.x;
  const int lane = tid & 63;
  const int wave = tid >> 6;            // 0..7
  const int wm   = wave >> 1;           // 0..3 -> m base wm*64
  const int wn   = wave & 1;            // 0..1 -> n base n0 + wn*32
  const int l15  = lane & 15;
  const int lq   = lane >> 4;

  // XCD-grouped decode: xcd = g&7 (dispatch round-robin); the 8 n-variants of
  // a c-chunk land on one XCD so its L2 dedups the shared A-slices.
  const int g   = blockIdx.x;
  const int n0  = ((g >> 3) & 7) * 64;
  const int cch = (g & 7) * 4 + (g >> 6);   // 0..31
  const int c0  = cch * 32;

  f32x4 acc[4][2] = {};                 // 32 AGPRs

  short *Aa = As[0], *Ab = As[1], *Ac = As[2];
  float *Wa = Ws[0], *Wb = Ws[1], *Wc = Ws[2];

  // prologue: steps 0,1 in flight (12 vmem ops/thread)
  stage_step(xT, W, Aa, Wa, tid, c0, 0, n0);
  stage_step(xT, W, Ab, Wb, tid, c0, 1, n0);

#pragma unroll 1
  for (int t = 0; t < 62; ++t) {
    const int tn = t + 2;
    stage_step(xT, W, Ac, Wc, tid, c0 + (tn >> 1), tn & 1, n0);
    asm volatile("s_waitcnt vmcnt(12)" ::: "memory");   // step t landed; t+1,t+2 fly
    __builtin_amdgcn_sched_barrier(0);
    __builtin_amdgcn_s_barrier();                       // all waves: step t ready
    compute_step(Aa, Wa, wm, wn, l15, lq, acc);
    __builtin_amdgcn_s_barrier();                       // slot reusable next iter
    short* ta = Aa; Aa = Ab; Ab = Ac; Ac = ta;          // rotate ring
    float* tw = Wa; Wa = Wb; Wb = Wc; Wc = tw;
  }
  // peeled tail: t = 62 (step 63 still in flight), then t = 63
  asm volatile("s_waitcnt vmcnt(6)" ::: "memory");
  __builtin_amdgcn_sched_barrier(0);
  __builtin_amdgcn_s_barrier();
  compute_step(Aa, Wa, wm, wn, l15, lq, acc);
  asm volatile("s_waitcnt vmcnt(0)" ::: "memory");
  __builtin_amdgcn_sched_barrier(0);
  __builtin_amdgcn_s_barrier();
  compute_step(Ab, Wb, wm, wn, l15, lq, acc);

  // epilogue: fold split-K partial into s_j (D layout: row=lq*4+r, col=l15)
#pragma unroll
  for (int mt = 0; mt < 4; ++mt) {
#pragma unroll
    for (int nt = 0; nt < 2; ++nt) {
      const int n = n0 + wn * 32 + nt * 16 + l15;
#pragma unroll
      for (int r = 0; r < 4; ++r) {
        const int brow = wm * 64 + mt * 16 + lq * 4 + r;
        atomicAdd(&sj[(size_t)brow * N_DIM + n], acc[mt][nt][r]);
      }
    }
  }
}

// ---------------------------------------------------------------------------
// Kernel 3: squash.  per (b,s): msq = sum_u s^2 ; v = s * sqrt(msq)/(1+msq)
// ---------------------------------------------------------------------------
__global__ void __launch_bounds__(512)
squash_kernel(const float* __restrict__ sj, float* __restrict__ out) {
  __shared__ float sm[512];
  const int b = blockIdx.x;
  const int t = threadIdx.x;
  const float v = sj[(size_t)b * N_DIM + t];
  sm[t] = v * v;
  __syncthreads();
#pragma unroll
  for (int off = 256; off >= 16; off >>= 1) {
    if (t < off) sm[t] += sm[t + off];
    __syncthreads();
  }
  const float msq   = sm[t & 15];
  const float scale = sqrtf(msq) / (1.0f + msq);
  out[(size_t)b * N_DIM + t] = v * scale;
}

// ---------------------------------------------------------------------------
extern "C" void kernel_launch(void* const* d_in, const int* in_sizes, int n_in,
                              void* d_out, int out_size, void* d_ws, size_t ws_size,
                              hipStream_t stream) {
  const float* x = (const float*)d_in[0];   // (256,128,1024) fp32
  const float* W = (const float*)d_in[1];   // (1,1024,32,16,128) fp32
  float* out = (float*)d_out;               // (256,32,16,1) fp32

  bf16*  xT = (bf16*)d_ws;                                  // 64 MiB
  float* sj = (float*)((char*)d_ws + (size_t)B_DIM * KC * sizeof(bf16));

  hipMemsetAsync(sj, 0, (size_t)B_DIM * N_DIM * sizeof(float), stream);
  transpose_cast<<<dim3(C_DIM / 64, I_DIM / 64, B_DIM), 256, 0, stream>>>(x, xT);
  gemm_kernel<<<dim3(256), 512, 0, stream>>>(xT, W, sj);
  squash_kernel<<<B_DIM, 512, 0, stream>>>(sj, out);
}

// Round 3
// 477.949 us; speedup vs baseline: 1.1510x; 1.0309x over previous
//
#include <hip/hip_runtime.h>
#include <hip/hip_bf16.h>
#include <stdint.h>

#define B_DIM 256
#define I_DIM 128
#define C_DIM 1024
#define N_DIM 512              // U*S
#define KC    (C_DIM * I_DIM)
#define WC    (N_DIM * I_DIM)
#define BI    (B_DIM * I_DIM)  // 32768: xc row stride per c

typedef __bf16 bf16;
typedef __attribute__((ext_vector_type(8))) __bf16 bf16x8;
typedef __attribute__((ext_vector_type(4))) float f32x4;

__device__ __forceinline__ void async_copy16(const void* g, void* l) {
  __builtin_amdgcn_global_load_lds(
      (const __attribute__((address_space(1))) uint32_t*)g,
      (__attribute__((address_space(3))) uint32_t*)l, 16, 0, 0);
}

// ---------------------------------------------------------------------------
// Kernel 1: xc[c][b][i] = (bf16) x[b][i][c].  c-major layout: gemm A-slices
// (fixed c, all b, i-half) are dense 32-KB blocks.  Same 64-MiB footprint.
// ---------------------------------------------------------------------------
__global__ void __launch_bounds__(256)
transpose_cast(const float* __restrict__ x, bf16* __restrict__ xc) {
  __shared__ float tile[64][65];
  const int c0 = blockIdx.x * 64;
  const int i0 = blockIdx.y * 64;
  const int b  = blockIdx.z;
  const int t  = threadIdx.x;
  const int sub = t >> 4;
  const int cg  = t & 15;
  const float* xb = x + (size_t)b * (I_DIM * C_DIM);
#pragma unroll
  for (int r = 0; r < 4; ++r) {
    const int i = r * 16 + sub;
    const float4 v = *(const float4*)&xb[(size_t)(i0 + i) * C_DIM + c0 + cg * 4];
    tile[i][cg * 4 + 0] = v.x; tile[i][cg * 4 + 1] = v.y;
    tile[i][cg * 4 + 2] = v.z; tile[i][cg * 4 + 3] = v.w;
  }
  __syncthreads();
#pragma unroll
  for (int r = 0; r < 2; ++r) {
    const int c  = r * 32 + (t >> 3);
    const int ic = (t & 7) * 8;
    bf16x8 o;
#pragma unroll
    for (int k = 0; k < 8; ++k) o[k] = (bf16)tile[ic + k][c];
    *(bf16x8*)&xc[(size_t)(c0 + c) * BI + (size_t)b * I_DIM + i0 + ic] = o;
  }
}

// ---------------------------------------------------------------------------
// Kernel 2: streaming split-K GEMM, LDS-traffic-balanced.
// Grid 256 = 4 n-blocks (Nt=128) x 64 c-chunks (16 c).  Bijective decode puts
// the 4 n-blocks of a chunk on ONE XCD (A-slice dedup'd in its L2 -> A read
// once from HBM chip-wide).  Waves: 2m x 4n -> LDS totals: A-write 256 MB,
// A-read 1 GB, W-write 256 MB, W-read 512 MB = 2.0 GB ~ 29 us << HBM 51 us.
// Step (c, h): A = xc[c][0:256][h*64:+64] dense 32 KB; W = W[c][n0:+128]
// [h*64:+64] = 128 x 256-B segments, 32 KB.  Ring-2 (128 KB LDS), 8 async
// ops/thread/step, vmcnt(8): one step landing + one queued at all times.
// Swizzles: A chunk ^= b&7 (2-way), W chunk ^= n&15 (2-way) on both sides.
// ---------------------------------------------------------------------------
__device__ __forceinline__ void stage_step(
    const bf16* __restrict__ xc, const float* __restrict__ W,
    short* Asl, float* Wsl, int tid, int c, int h, int n0) {
  // A: 2048 16-B chunks (b, ch): LDS linear, source chunk XOR'd by b&7.
  const size_t abase = (size_t)c * BI + h * 64;
#pragma unroll
  for (int p = 0; p < 4; ++p) {
    const int g  = p * 512 + tid;
    const int b  = g >> 3;
    const int cs = (g & 7) ^ (b & 7);
    async_copy16(xc + abase + (size_t)b * I_DIM + cs * 8, Asl + (size_t)g * 8);
  }
  // W: 2048 16-B chunks (n, q): 16 chunks/row, source chunk XOR'd by n&15.
  const size_t wbase = (size_t)c * WC + (size_t)n0 * I_DIM + h * 64;
#pragma unroll
  for (int p = 0; p < 4; ++p) {
    const int g  = p * 512 + tid;
    const int n  = g >> 4;
    const int qs = (g & 15) ^ (n & 15);
    async_copy16(W + wbase + (size_t)n * I_DIM + qs * 4, Wsl + (size_t)g * 4);
  }
}

__device__ __forceinline__ void compute_step(
    const short* As, const float* Wl,
    int wm, int wn2, int l15, int lq, f32x4 (&acc)[8][2]) {
  const int m7 = l15 & 7;
#pragma unroll
  for (int ksl = 0; ksl < 2; ++ksl) {
    bf16x8 a[8];
#pragma unroll
    for (int mt = 0; mt < 8; ++mt) {
      const int m  = wm * 128 + mt * 16 + l15;
      const int st = (ksl * 4 + lq) ^ m7;
      a[mt] = *(const bf16x8*)&As[m * 64 + st * 8];
    }
    bf16x8 b[2];
#pragma unroll
    for (int nt = 0; nt < 2; ++nt) {
      const int n  = wn2 * 32 + nt * 16 + l15;       // row in 128-row W tile
      const int q0 = ksl * 8 + lq * 2;
      const f32x4 lo = *(const f32x4*)&Wl[n * 64 + ((q0 ^ l15) * 4)];
      const f32x4 hi = *(const f32x4*)&Wl[n * 64 + (((q0 + 1) ^ l15) * 4)];
      bf16x8 bb;
      bb[0] = (bf16)lo[0]; bb[1] = (bf16)lo[1];
      bb[2] = (bf16)lo[2]; bb[3] = (bf16)lo[3];
      bb[4] = (bf16)hi[0]; bb[5] = (bf16)hi[1];
      bb[6] = (bf16)hi[2]; bb[7] = (bf16)hi[3];
      b[nt] = bb;
    }
#pragma unroll
    for (int mt = 0; mt < 8; ++mt)
#pragma unroll
      for (int nt = 0; nt < 2; ++nt)
        acc[mt][nt] = __builtin_amdgcn_mfma_f32_16x16x32_bf16(
            a[mt], b[nt], acc[mt][nt], 0, 0, 0);
  }
}

__global__ void __launch_bounds__(512, 2)
gemm_kernel(const bf16* __restrict__ xc, const float* __restrict__ W,
            float* __restrict__ sj) {
  __shared__ short As[2][B_DIM * 64];   // 2 x 32 KB
  __shared__ float Wl[2][128 * 64];     // 2 x 32 KB -> 128 KB total
  const int tid  = threadIdx.x;
  const int lane = tid & 63;
  const int wv   = tid >> 6;
  const int wm   = wv >> 2;            // 0..1 -> m base wm*128
  const int wn2  = wv & 3;             // 0..3 -> n base n0 + wn2*32
  const int l15  = lane & 15;
  const int lq   = lane >> 4;

  // bijective decode; the 4 n-blocks of a chunk share XCD (g%8 dispatch).
  const int g     = blockIdx.x;
  const int chunk = (g & 7) * 8 + ((g >> 3) & 7);   // 0..63
  const int nb    = g >> 6;                          // 0..3
  const int n0    = nb * 128;
  const int c0    = chunk * 16;

  f32x4 acc[8][2] = {};                // 64 acc regs

  // prologue: step 0 -> slot 0
  stage_step(xc, W, As[0], Wl[0], tid, c0, 0, n0);

#pragma unroll 1
  for (int t = 0; t < 31; ++t) {       // 32 steps = 16 c x 2 i-halves
    const int tn = t + 1;
    stage_step(xc, W, As[tn & 1], Wl[tn & 1], tid, c0 + (tn >> 1), tn & 1, n0);
    asm volatile("s_waitcnt vmcnt(8)" ::: "memory");   // step t landed
    __builtin_amdgcn_sched_barrier(0);
    __builtin_amdgcn_s_barrier();
    compute_step(As[t & 1], Wl[t & 1], wm, wn2, l15, lq, acc);
    __builtin_amdgcn_s_barrier();      // slot reusable next iter
  }
  asm volatile("s_waitcnt vmcnt(0)" ::: "memory");
  __builtin_amdgcn_sched_barrier(0);
  __builtin_amdgcn_s_barrier();
  compute_step(As[1], Wl[1], wm, wn2, l15, lq, acc);

  // epilogue: split-K partial -> sj (D layout: row = lq*4+r, col = l15)
#pragma unroll
  for (int mt = 0; mt < 8; ++mt) {
#pragma unroll
    for (int nt = 0; nt < 2; ++nt) {
      const int n = n0 + wn2 * 32 + nt * 16 + l15;
#pragma unroll
      for (int r = 0; r < 4; ++r) {
        const int brow = wm * 128 + mt * 16 + lq * 4 + r;
        atomicAdd(&sj[(size_t)brow * N_DIM + n], acc[mt][nt][r]);
      }
    }
  }
}

// ---------------------------------------------------------------------------
// Kernel 3: squash.  per (b,s): msq = sum_u s^2 ; v = s * sqrt(msq)/(1+msq)
// ---------------------------------------------------------------------------
__global__ void __launch_bounds__(512)
squash_kernel(const float* __restrict__ sj, float* __restrict__ out) {
  __shared__ float sm[512];
  const int b = blockIdx.x;
  const int t = threadIdx.x;
  const float v = sj[(size_t)b * N_DIM + t];
  sm[t] = v * v;
  __syncthreads();
#pragma unroll
  for (int off = 256; off >= 16; off >>= 1) {
    if (t < off) sm[t] += sm[t + off];
    __syncthreads();
  }
  const float msq   = sm[t & 15];
  const float scale = sqrtf(msq) / (1.0f + msq);
  out[(size_t)b * N_DIM + t] = v * scale;
}

// ---------------------------------------------------------------------------
extern "C" void kernel_launch(void* const* d_in, const int* in_sizes, int n_in,
                              void* d_out, int out_size, void* d_ws, size_t ws_size,
                              hipStream_t stream) {
  const float* x = (const float*)d_in[0];   // (256,128,1024) fp32
  const float* W = (const float*)d_in[1];   // (1,1024,32,16,128) fp32
  float* out = (float*)d_out;               // (256,32,16,1) fp32

  bf16*  xc = (bf16*)d_ws;                                  // 64 MiB exactly
  float* sj = (float*)((char*)d_ws + (size_t)KC * B_DIM * sizeof(bf16));

  hipMemsetAsync(sj, 0, (size_t)B_DIM * N_DIM * sizeof(float), stream);
  transpose_cast<<<dim3(C_DIM / 64, I_DIM / 64, B_DIM), 256, 0, stream>>>(x, xc);
  gemm_kernel<<<dim3(256), 512, 0, stream>>>(xc, W, sj);
  squash_kernel<<<B_DIM, 512, 0, stream>>>(sj, out);
}